// Round 7
// baseline (626.445 us; speedup 1.0000x reference)
//
#include <hip/hip_runtime.h>
#include <hip/hip_bf16.h>

// ---------------- problem constants ----------------
#define N_NODES   100000
#define IN_DIM    256
#define OUT_DIM   256
#define N_REL     8
#define E_PER_REL 160000
#define N_EDGES   (N_REL * E_PER_REL)      // 1,280,000
#define N_COLS    ((N_REL + 1) * OUT_DIM)  // 2304 logical: rel blocks 0..7, self block 8
#define LN_EPS    1e-5f

// column phasing: 4 phases x 64 columns; H chunk holds 9 rel-blocks x 64 cols
#define CPH 64
#define N_PHASE 4
#define HC  (9 * CPH)   // 576 cols per H row

// CSR bucket pipeline
#define NB   256
#define NPB  391
#define ECHUNK 4096
#define NWGE ((N_EDGES + ECHUNK - 1) / ECHUNK)   // 313

typedef unsigned short ushort_t;
typedef unsigned int   uint_t;

typedef __attribute__((ext_vector_type(8))) __bf16    bf16x8;
typedef __attribute__((ext_vector_type(4))) float     f32x4;

__device__ __forceinline__ ushort_t f2bf(float f) {
    uint_t x = __float_as_uint(f);
    x += 0x7FFFu + ((x >> 16) & 1u);
    return (ushort_t)(x >> 16);
}
__device__ __forceinline__ float bf_lo(uint_t u) { return __uint_as_float(u << 16); }
__device__ __forceinline__ float bf_hi(uint_t u) { return __uint_as_float(u & 0xFFFF0000u); }

__device__ __forceinline__ void gload16(const void* g, void* l) {
    __builtin_amdgcn_global_load_lds(
        (const __attribute__((address_space(1))) void*)g,
        (__attribute__((address_space(3))) void*)l, 16, 0, 0);
}

// ---------------- x fp32 -> bf16 (once) ----------------
__global__ void conv_x_kernel(const float* __restrict__ x, ushort_t* __restrict__ xb) {
    int i = blockIdx.x * 256 + threadIdx.x;
    if (i >= N_NODES * IN_DIM / 8) return;
    const float4* p = (const float4*)x + (size_t)i * 2;
    float4 f0 = p[0], f1 = p[1];
    __hip_bfloat162 h0 = __float22bfloat162_rn(make_float2(f0.x, f0.y));
    __hip_bfloat162 h1 = __float22bfloat162_rn(make_float2(f0.z, f0.w));
    __hip_bfloat162 h2 = __float22bfloat162_rn(make_float2(f1.x, f1.y));
    __hip_bfloat162 h3 = __float22bfloat162_rn(make_float2(f1.z, f1.w));
    uint4 pv;
    __builtin_memcpy(&pv.x, &h0, 4);
    __builtin_memcpy(&pv.y, &h1, 4);
    __builtin_memcpy(&pv.z, &h2, 4);
    __builtin_memcpy(&pv.w, &h3, 4);
    *(uint4*)(xb + (size_t)i * 8) = pv;
}

// ---------------- prep: BT[n][k], n = r*256+c (r<8 rel, r==8 self) ----------------
__global__ void prep_w_kernel(const float* __restrict__ Wself, const float* __restrict__ rel,
                              ushort_t* __restrict__ BT) {
    int i = blockIdx.x * 256 + threadIdx.x;
    if (i >= N_COLS * IN_DIM) return;
    int n = i >> 8, k = i & 255;
    int r = n >> 8, c = n & 255;
    float v = (r < N_REL) ? rel[(((r << 8) + k) << 8) + c] : Wself[(k << 8) + c];
    BT[i] = f2bf(v);
}

// ---------------- CSR build: bucketed multi-split ----------------
__global__ __launch_bounds__(256) void count_buckets(const int* __restrict__ dst,
                                                     int* __restrict__ g_bcount) {
    __shared__ int cnt[NB];
    int tid = threadIdx.x;
    cnt[tid] = 0;
    __syncthreads();
    #pragma unroll
    for (int it = 0; it < 4; ++it) {
        int e = blockIdx.x * ECHUNK + it * 1024 + tid * 4;
        if (e < N_EDGES) {
            int4 d = *(const int4*)(dst + e);
            atomicAdd(&cnt[(uint_t)d.x / NPB], 1);
            atomicAdd(&cnt[(uint_t)d.y / NPB], 1);
            atomicAdd(&cnt[(uint_t)d.z / NPB], 1);
            atomicAdd(&cnt[(uint_t)d.w / NPB], 1);
        }
    }
    __syncthreads();
    if (cnt[tid]) atomicAdd(&g_bcount[tid], cnt[tid]);
}

__global__ __launch_bounds__(256) void scan_buckets(const int* __restrict__ g_bcount,
                                                    int* __restrict__ g_bbase,
                                                    int* __restrict__ g_bcursor) {
    __shared__ int wsum[4];
    int tid = threadIdx.x, lane = tid & 63, w = tid >> 6;
    int val = g_bcount[tid];
    int x = val;
    #pragma unroll
    for (int d = 1; d < 64; d <<= 1) {
        int y = __shfl_up(x, d, 64);
        if (lane >= d) x += y;
    }
    if (lane == 63) wsum[w] = x;
    __syncthreads();
    if (tid == 0) {
        int a = 0;
        #pragma unroll
        for (int k = 0; k < 4; ++k) { int t = wsum[k]; wsum[k] = a; a += t; }
    }
    __syncthreads();
    int excl = wsum[w] + x - val;
    g_bbase[tid] = excl;
    g_bcursor[tid] = excl;
    if (tid == 255) g_bbase[256] = excl + val;
}

__global__ __launch_bounds__(256) void scatter_buckets(const int* __restrict__ src,
                                                       const int* __restrict__ dst,
                                                       int* __restrict__ g_bcursor,
                                                       uint2* __restrict__ tmp) {
    __shared__ int cnt[NB];
    __shared__ int basec[NB];
    int tid = threadIdx.x;
    cnt[tid] = 0;
    __syncthreads();
    #pragma unroll
    for (int it = 0; it < 4; ++it) {
        int e = blockIdx.x * ECHUNK + it * 1024 + tid * 4;
        if (e < N_EDGES) {
            int4 d = *(const int4*)(dst + e);
            atomicAdd(&cnt[(uint_t)d.x / NPB], 1);
            atomicAdd(&cnt[(uint_t)d.y / NPB], 1);
            atomicAdd(&cnt[(uint_t)d.z / NPB], 1);
            atomicAdd(&cnt[(uint_t)d.w / NPB], 1);
        }
    }
    __syncthreads();
    basec[tid] = cnt[tid] ? atomicAdd(&g_bcursor[tid], cnt[tid]) : 0;
    __syncthreads();
    cnt[tid] = 0;
    __syncthreads();
    #pragma unroll
    for (int it = 0; it < 4; ++it) {
        int e = blockIdx.x * ECHUNK + it * 1024 + tid * 4;
        if (e < N_EDGES) {
            int4 d = *(const int4*)(dst + e);
            int4 s = *(const int4*)(src + e);
            uint_t relb = ((uint_t)e / E_PER_REL) << 20;
            uint_t b0 = (uint_t)d.x / NPB, b1 = (uint_t)d.y / NPB;
            uint_t b2 = (uint_t)d.z / NPB, b3 = (uint_t)d.w / NPB;
            int p0 = basec[b0] + atomicAdd(&cnt[b0], 1);
            tmp[p0] = make_uint2((uint_t)d.x, (uint_t)s.x | relb);
            int p1 = basec[b1] + atomicAdd(&cnt[b1], 1);
            tmp[p1] = make_uint2((uint_t)d.y, (uint_t)s.y | relb);
            int p2 = basec[b2] + atomicAdd(&cnt[b2], 1);
            tmp[p2] = make_uint2((uint_t)d.z, (uint_t)s.z | relb);
            int p3 = basec[b3] + atomicAdd(&cnt[b3], 1);
            tmp[p3] = make_uint2((uint_t)d.w, (uint_t)s.w | relb);
        }
    }
}

__global__ __launch_bounds__(256) void build_csr(const uint2* __restrict__ tmp,
                                                 const int* __restrict__ g_bbase,
                                                 int* __restrict__ offs,
                                                 uint_t* __restrict__ edges) {
    __shared__ int cnt[NPB];
    __shared__ int sc[512];
    int b = blockIdx.x, tid = threadIdx.x;
    int node0 = b * NPB;
    int nn = min(NPB, N_NODES - node0);
    int r0 = g_bbase[b], r1 = g_bbase[b + 1];

    for (int i = tid; i < NPB; i += 256) cnt[i] = 0;
    __syncthreads();
    for (int i = r0 + tid; i < r1; i += 256) {
        uint2 rec = tmp[i];
        atomicAdd(&cnt[rec.x - node0], 1);
    }
    __syncthreads();
    sc[tid]       = (tid < NPB) ? cnt[tid] : 0;
    sc[tid + 256] = (tid + 256 < NPB) ? cnt[tid + 256] : 0;
    __syncthreads();
    for (int d = 1; d < 512; d <<= 1) {
        int a  = (tid >= d) ? sc[tid - d] : 0;
        int a2 = (tid + 256 >= d) ? sc[tid + 256 - d] : 0;
        __syncthreads();
        sc[tid] += a; sc[tid + 256] += a2;
        __syncthreads();
    }
    for (int i = tid; i < NPB; i += 256) {
        int ex = r0 + sc[i] - cnt[i];
        if (i < nn) offs[node0 + i] = ex;
        cnt[i] = ex;
    }
    if (b == NB - 1 && tid == 0) offs[N_NODES] = r1;
    __syncthreads();
    for (int i = r0 + tid; i < r1; i += 256) {
        uint2 rec = tmp[i];
        int pos = atomicAdd(&cnt[rec.x - node0], 1);
        edges[pos] = rec.y;
    }
}

// ---------------- phase GEMM: H[M][576] = X[M][256] @ BT[sel rows][256]^T ----------
// 128 rows x 3 rel-blocks x 64 cols per block; counted-vmcnt 2-phase pipeline.
#define BM 128
#define BN 64
#define BK 64
#define KT 256
#define RB 3
#define EPAD 72
#define BUFSH (BM * BK + RB * BN * BK)   // 20480 shorts = 40960 B per buffer

__device__ __forceinline__ void stage_tile(ushort_t* smem, int bufofs, int kk,
                                           int m0, int rb0, int c0, int M,
                                           const ushort_t* __restrict__ X,
                                           const ushort_t* __restrict__ B, int tid) {
    #pragma unroll
    for (int i = 0; i < 4; ++i) {
        int g = i * 256 + tid;
        int r = g >> 3, sc2 = g & 7, c = sc2 ^ (r & 7);
        int gr = m0 + r; if (gr >= M) gr = M - 1;
        gload16(X + (size_t)gr * KT + kk + c * 8, &smem[bufofs + g * 8]);
    }
    #pragma unroll
    for (int t = 0; t < RB; ++t) {
        int bofs = bufofs + BM * BK + t * BN * BK;
        #pragma unroll
        for (int i = 0; i < 2; ++i) {
            int g = i * 256 + tid;
            int r = g >> 3, sc2 = g & 7, c = sc2 ^ (r & 7);
            int nrow = (rb0 + t) * 256 + c0 + r;
            gload16(B + (size_t)nrow * KT + kk + c * 8, &smem[bofs + g * 8]);
        }
    }
}

__device__ __forceinline__ void gemm_tile(int tile, const ushort_t* __restrict__ X,
                                          const ushort_t* __restrict__ B,
                                          ushort_t* __restrict__ H, int M, int c0,
                                          ushort_t* smem) {
    const int rb0 = (tile % 3) * RB;
    const int m0  = (tile / 3) * BM;
    const int tid  = threadIdx.x;
    const int lane = tid & 63;
    const int w = tid >> 6;
    const int quad = lane >> 4, m16 = lane & 15;
    const int wm = (w & 1) * 64, wn = (w >> 1) * 32;

    f32x4 acc[RB][4][2];
    #pragma unroll
    for (int t = 0; t < RB; ++t)
        #pragma unroll
        for (int mi = 0; mi < 4; ++mi)
            #pragma unroll
            for (int ni = 0; ni < 2; ++ni)
                #pragma unroll
                for (int e = 0; e < 4; ++e) acc[t][mi][ni][e] = 0.f;

    stage_tile(smem, 0, 0, m0, rb0, c0, M, X, B, tid);

    #pragma unroll
    for (int it = 0; it < 4; ++it) {
        const int cbuf = (it & 1) * BUFSH;
        if (it < 3)
            stage_tile(smem, ((it + 1) & 1) * BUFSH, (it + 1) * BK, m0, rb0, c0, M, X, B, tid);
        if (it < 3) asm volatile("s_waitcnt vmcnt(10)" ::: "memory");
        else        asm volatile("s_waitcnt vmcnt(0)" ::: "memory");
        __builtin_amdgcn_s_barrier();
        __builtin_amdgcn_sched_barrier(0);

        #pragma unroll
        for (int ks = 0; ks < BK; ks += 32) {
            int chunk = (ks >> 3) + quad;
            bf16x8 af[4];
            #pragma unroll
            for (int mi = 0; mi < 4; ++mi) {
                int row = wm + mi * 16 + m16;
                af[mi] = *(const bf16x8*)(&smem[cbuf + (row * 8 + (chunk ^ (row & 7))) * 8]);
            }
            #pragma unroll
            for (int t = 0; t < RB; ++t) {
                const ushort_t* Bs = smem + cbuf + BM * BK + t * BN * BK;
                bf16x8 bfr[2];
                #pragma unroll
                for (int ni = 0; ni < 2; ++ni) {
                    int row = wn + ni * 16 + m16;
                    bfr[ni] = *(const bf16x8*)(&Bs[(row * 8 + (chunk ^ (row & 7))) * 8]);
                }
                #pragma unroll
                for (int mi = 0; mi < 4; ++mi)
                    #pragma unroll
                    for (int ni = 0; ni < 2; ++ni)
                        acc[t][mi][ni] = __builtin_amdgcn_mfma_f32_16x16x32_bf16(
                            af[mi], bfr[ni], acc[t][mi][ni], 0, 0, 0);
            }
        }
        __builtin_amdgcn_s_barrier();
    }

    #pragma unroll
    for (int t = 0; t < RB; ++t) {
        #pragma unroll
        for (int mi = 0; mi < 4; ++mi)
            #pragma unroll
            for (int ni = 0; ni < 2; ++ni) {
                int col = wn + ni * 16 + m16;
                int rowb = wm + mi * 16 + quad * 4;
                #pragma unroll
                for (int rg = 0; rg < 4; ++rg)
                    smem[(rowb + rg) * EPAD + col] = f2bf(acc[t][mi][ni][rg]);
            }
        __syncthreads();
        #pragma unroll
        for (int i = 0; i < 4; ++i) {
            int cch = i * 256 + tid;
            int row = cch >> 3, col8 = (cch & 7) * 8;
            int grow = m0 + row;
            if (grow < M) {
                uint4 v = *(const uint4*)(&smem[row * EPAD + col8]);
                *(uint4*)(H + (size_t)grow * HC + (rb0 + t) * CPH + col8) = v;
            }
        }
        __syncthreads();
    }
}

// ---------------- standalone GEMM ----------------
template <bool BF16X>
__global__ __launch_bounds__(256) void gemm_kernel(const void* __restrict__ Xv,
                                                   const ushort_t* __restrict__ B,
                                                   ushort_t* __restrict__ H,
                                                   int M, int c0) {
    __shared__ ushort_t smem[BF16X ? 2 * BUFSH : BUFSH];
    const int nwg  = gridDim.x * gridDim.y;
    const int orig = blockIdx.y * gridDim.x + blockIdx.x;
    const int q8 = nwg >> 3, r8 = nwg & 7;
    const int xcd = orig & 7, loc = orig >> 3;
    const int swz = (xcd < r8 ? xcd * (q8 + 1) : r8 * (q8 + 1) + (xcd - r8) * q8) + loc;

    if (BF16X) {
        gemm_tile(swz, (const ushort_t*)Xv, B, H, M, c0, smem);
        return;
    }

    // fp32 fallback: reg-staged with convert (single buffer, 2-barrier loop)
    ushort_t* As = smem;
    const int rb0 = (swz % 3) * RB;
    const int m0  = (swz / 3) * BM;
    const int tid  = threadIdx.x;
    const int lane = tid & 63, w = tid >> 6;
    const int quad = lane >> 4, m16 = lane & 15;
    const int wm = (w & 1) * 64, wn = (w >> 1) * 32;

    f32x4 acc[RB][4][2];
    #pragma unroll
    for (int t = 0; t < RB; ++t)
        #pragma unroll
        for (int mi = 0; mi < 4; ++mi)
            #pragma unroll
            for (int ni = 0; ni < 2; ++ni)
                #pragma unroll
                for (int e = 0; e < 4; ++e) acc[t][mi][ni][e] = 0.f;

    for (int kk = 0; kk < KT; kk += BK) {
        #pragma unroll
        for (int i = 0; i < 4; ++i) {
            int g = i * 256 + tid;
            int r = g >> 3, sc2 = g & 7, c = sc2 ^ (r & 7);
            int gr = m0 + r; if (gr >= M) gr = M - 1;
            const float* X = (const float*)Xv;
            const float* sp = X + (size_t)gr * KT + kk + c * 8;
            float4 f0 = *(const float4*)sp;
            float4 f1 = *(const float4*)(sp + 4);
            __hip_bfloat162 h0 = __float22bfloat162_rn(make_float2(f0.x, f0.y));
            __hip_bfloat162 h1 = __float22bfloat162_rn(make_float2(f0.z, f0.w));
            __hip_bfloat162 h2 = __float22bfloat162_rn(make_float2(f1.x, f1.y));
            __hip_bfloat162 h3 = __float22bfloat162_rn(make_float2(f1.z, f1.w));
            uint4 pv;
            __builtin_memcpy(&pv.x, &h0, 4);
            __builtin_memcpy(&pv.y, &h1, 4);
            __builtin_memcpy(&pv.z, &h2, 4);
            __builtin_memcpy(&pv.w, &h3, 4);
            *(uint4*)(&As[g * 8]) = pv;
        }
        #pragma unroll
        for (int t = 0; t < RB; ++t) {
            ushort_t* Bs = smem + BM * BK + t * BN * BK;
            #pragma unroll
            for (int i = 0; i < 2; ++i) {
                int g = i * 256 + tid;
                int r = g >> 3, sc2 = g & 7, c = sc2 ^ (r & 7);
                int nrow = (rb0 + t) * 256 + c0 + r;
                *(uint4*)(&Bs[g * 8]) = *(const uint4*)(B + (size_t)nrow * KT + kk + c * 8);
            }
        }
        __syncthreads();

        #pragma unroll
        for (int ks = 0; ks < BK; ks += 32) {
            int chunk = (ks >> 3) + quad;
            bf16x8 af[4];
            #pragma unroll
            for (int mi = 0; mi < 4; ++mi) {
                int row = wm + mi * 16 + m16;
                af[mi] = *(const bf16x8*)(&As[(row * 8 + (chunk ^ (row & 7))) * 8]);
            }
            #pragma unroll
            for (int t = 0; t < RB; ++t) {
                const ushort_t* Bs = smem + BM * BK + t * BN * BK;
                bf16x8 bfr[2];
                #pragma unroll
                for (int ni = 0; ni < 2; ++ni) {
                    int row = wn + ni * 16 + m16;
                    bfr[ni] = *(const bf16x8*)(&Bs[(row * 8 + (chunk ^ (row & 7))) * 8]);
                }
                #pragma unroll
                for (int mi = 0; mi < 4; ++mi)
                    #pragma unroll
                    for (int ni = 0; ni < 2; ++ni)
                        acc[t][mi][ni] = __builtin_amdgcn_mfma_f32_16x16x32_bf16(
                            af[mi], bfr[ni], acc[t][mi][ni], 0, 0, 0);
            }
        }
        __syncthreads();
    }

    #pragma unroll
    for (int t = 0; t < RB; ++t) {
        #pragma unroll
        for (int mi = 0; mi < 4; ++mi)
            #pragma unroll
            for (int ni = 0; ni < 2; ++ni) {
                int col = wn + ni * 16 + m16;
                int rowb = wm + mi * 16 + quad * 4;
                #pragma unroll
                for (int rg = 0; rg < 4; ++rg)
                    smem[(rowb + rg) * EPAD + col] = f2bf(acc[t][mi][ni][rg]);
            }
        __syncthreads();
        #pragma unroll
        for (int i = 0; i < 4; ++i) {
            int cch = i * 256 + tid;
            int row = cch >> 3, col8 = (cch & 7) * 8;
            int grow = m0 + row;
            if (grow < M) {
                uint4 v = *(const uint4*)(&smem[row * EPAD + col8]);
                *(uint4*)(H + (size_t)grow * HC + (rb0 + t) * CPH + col8) = v;
            }
        }
        __syncthreads();
    }
}

// ---------------- gather, 2 nodes/wave, LDS-staged edge windows ----------------
// In-flight loads land in LDS (no VGPR cost): wave stages up to 16 edges x 2 nodes
// (4KB/wave, 16KB/block, full 32-wave/CU occupancy), one vmcnt(0) per round.
#define GW 16   // edges per node per stage round
__global__ __launch_bounds__(256) void gather2_kernel(const ushort_t* __restrict__ H,
                                                      const int* __restrict__ offs,
                                                      const uint_t* __restrict__ edges,
                                                      float* __restrict__ out, int c0) {
    __shared__ ushort_t gbuf[4][2][GW * 64];   // [wave][node][slot*128B]
    int w = threadIdx.x >> 6, lane = threadIdx.x & 63;
    int n0 = blockIdx.x * 8 + w * 2;           // grid 12500 -> exact coverage
    int grp = lane >> 3, cs = (lane & 7) * 8;

    float a0=0.f,a1=0.f,a2=0.f,a3=0.f,a4=0.f,a5=0.f,a6=0.f,a7=0.f;
    float b0=0.f,b1=0.f,b2=0.f,b3=0.f,b4=0.f,b5=0.f,b6=0.f,b7=0.f;
    if (grp == 7) {   // self of n0 (once)
        uint4 v = *(const uint4*)(H + (size_t)n0 * HC + 512 + cs);
        a0 += bf_lo(v.x); a1 += bf_hi(v.x); a2 += bf_lo(v.y); a3 += bf_hi(v.y);
        a4 += bf_lo(v.z); a5 += bf_hi(v.z); a6 += bf_lo(v.w); a7 += bf_hi(v.w);
    }
    if (grp == 6) {   // self of n1 (once)
        uint4 v = *(const uint4*)(H + (size_t)(n0 + 1) * HC + 512 + cs);
        b0 += bf_lo(v.x); b1 += bf_hi(v.x); b2 += bf_lo(v.y); b3 += bf_hi(v.y);
        b4 += bf_lo(v.z); b5 += bf_hi(v.z); b6 += bf_lo(v.w); b7 += bf_hi(v.w);
    }
    int e0a = offs[n0], e1a = offs[n0 + 1], e1b = offs[n0 + 2];
    int ra = e0a, rb = e1a;
    while (ra < e1a || rb < e1b) {
        // stage: per j one gload16 = 8 edges x 128B, LDS dest linear in lane (HW layout)
        if (ra < e1a) {
            #pragma unroll
            for (int j = 0; j < 2; ++j) {
                int ia = ra + j * 8 + grp;
                if (ia < e1a) {
                    uint_t r = edges[ia];
                    gload16(H + (size_t)(r & 0xFFFFFu) * HC + ((r >> 20) << 6) + cs,
                            &gbuf[w][0][j * 512 + lane * 8]);
                }
            }
        }
        if (rb < e1b) {
            #pragma unroll
            for (int j = 0; j < 2; ++j) {
                int ib = rb + j * 8 + grp;
                if (ib < e1b) {
                    uint_t r = edges[ib];
                    gload16(H + (size_t)(r & 0xFFFFFu) * HC + ((r >> 20) << 6) + cs,
                            &gbuf[w][1][j * 512 + lane * 8]);
                }
            }
        }
        asm volatile("s_waitcnt vmcnt(0)" ::: "memory");
        // consume: each lane reads back exactly its own slot (conflict-free)
        if (ra < e1a) {
            #pragma unroll
            for (int j = 0; j < 2; ++j) {
                int ia = ra + j * 8 + grp;
                if (ia < e1a) {
                    uint4 v = *(const uint4*)(&gbuf[w][0][j * 512 + lane * 8]);
                    a0 += bf_lo(v.x); a1 += bf_hi(v.x); a2 += bf_lo(v.y); a3 += bf_hi(v.y);
                    a4 += bf_lo(v.z); a5 += bf_hi(v.z); a6 += bf_lo(v.w); a7 += bf_hi(v.w);
                }
            }
            ra += GW;
        }
        if (rb < e1b) {
            #pragma unroll
            for (int j = 0; j < 2; ++j) {
                int ib = rb + j * 8 + grp;
                if (ib < e1b) {
                    uint4 v = *(const uint4*)(&gbuf[w][1][j * 512 + lane * 8]);
                    b0 += bf_lo(v.x); b1 += bf_hi(v.x); b2 += bf_lo(v.y); b3 += bf_hi(v.y);
                    b4 += bf_lo(v.z); b5 += bf_hi(v.z); b6 += bf_lo(v.w); b7 += bf_hi(v.w);
                }
            }
            rb += GW;
        }
    }
    #pragma unroll
    for (int off = 8; off <= 32; off <<= 1) {
        a0 += __shfl_xor(a0, off, 64); a1 += __shfl_xor(a1, off, 64);
        a2 += __shfl_xor(a2, off, 64); a3 += __shfl_xor(a3, off, 64);
        a4 += __shfl_xor(a4, off, 64); a5 += __shfl_xor(a5, off, 64);
        a6 += __shfl_xor(a6, off, 64); a7 += __shfl_xor(a7, off, 64);
        b0 += __shfl_xor(b0, off, 64); b1 += __shfl_xor(b1, off, 64);
        b2 += __shfl_xor(b2, off, 64); b3 += __shfl_xor(b3, off, 64);
        b4 += __shfl_xor(b4, off, 64); b5 += __shfl_xor(b5, off, 64);
        b6 += __shfl_xor(b6, off, 64); b7 += __shfl_xor(b7, off, 64);
    }
    if (grp == 0) {
        float* op = out + (size_t)n0 * OUT_DIM + c0 + cs;
        *(float4*)op       = make_float4(a0, a1, a2, a3);
        *(float4*)(op + 4) = make_float4(a4, a5, a6, a7);
    }
    if (grp == 1) {
        float* op = out + (size_t)(n0 + 1) * OUT_DIM + c0 + cs;
        *(float4*)op       = make_float4(b0, b1, b2, b3);
        *(float4*)(op + 4) = make_float4(b4, b5, b6, b7);
    }
}

// ---------------- phase-3 gather fused with LayerNorm ----------------
// The wave computing a node's cols 192..255 keeps them in registers/LDS and
// normalizes the whole row: saves the 64-col write+read round trip + LN dispatch.
__global__ __launch_bounds__(256) void gather_ln_kernel(const ushort_t* __restrict__ H,
                                                        const int* __restrict__ offs,
                                                        const uint_t* __restrict__ edges,
                                                        float* __restrict__ out,
                                                        const float* __restrict__ gamma,
                                                        const float* __restrict__ beta) {
    __shared__ float lns[4][64];
    int w = threadIdx.x >> 6, lane = threadIdx.x & 63;
    int node = blockIdx.x * 4 + w;             // grid 25000 -> exact coverage
    int grp = lane >> 3, cs = (lane & 7) * 8;
    const int c0 = 3 * CPH;                    // 192

    float a0=0.f,a1=0.f,a2=0.f,a3=0.f,a4=0.f,a5=0.f,a6=0.f,a7=0.f;
    if (grp == 7) {
        uint4 v = *(const uint4*)(H + (size_t)node * HC + 512 + cs);
        a0 += bf_lo(v.x); a1 += bf_hi(v.x); a2 += bf_lo(v.y); a3 += bf_hi(v.y);
        a4 += bf_lo(v.z); a5 += bf_hi(v.z); a6 += bf_lo(v.w); a7 += bf_hi(v.w);
    }
    int e0 = offs[node], e1 = offs[node + 1];
    for (int base = e0; base < e1; base += 32) {
        #pragma unroll
        for (int j = 0; j < 4; ++j) {
            int idx = base + j * 8 + grp;
            if (idx < e1) {
                uint_t r = edges[idx];
                uint4 v = *(const uint4*)(H + (size_t)(r & 0xFFFFFu) * HC + ((r >> 20) << 6) + cs);
                a0 += bf_lo(v.x); a1 += bf_hi(v.x); a2 += bf_lo(v.y); a3 += bf_hi(v.y);
                a4 += bf_lo(v.z); a5 += bf_hi(v.z); a6 += bf_lo(v.w); a7 += bf_hi(v.w);
            }
        }
    }
    #pragma unroll
    for (int off = 8; off <= 32; off <<= 1) {
        a0 += __shfl_xor(a0, off, 64); a1 += __shfl_xor(a1, off, 64);
        a2 += __shfl_xor(a2, off, 64); a3 += __shfl_xor(a3, off, 64);
        a4 += __shfl_xor(a4, off, 64); a5 += __shfl_xor(a5, off, 64);
        a6 += __shfl_xor(a6, off, 64); a7 += __shfl_xor(a7, off, 64);
    }
    if (grp == 0) {
        lns[w][cs + 0] = a0; lns[w][cs + 1] = a1; lns[w][cs + 2] = a2; lns[w][cs + 3] = a3;
        lns[w][cs + 4] = a4; lns[w][cs + 5] = a5; lns[w][cs + 6] = a6; lns[w][cs + 7] = a7;
    }
    __syncthreads();

    int c4 = lane * 4;
    float4 v;
    if (c4 < 192) {
        v = *(const float4*)(out + (size_t)node * OUT_DIM + c4);
    } else {
        v.x = lns[w][c4 - 192]; v.y = lns[w][c4 - 191];
        v.z = lns[w][c4 - 190]; v.w = lns[w][c4 - 189];
    }
    float s = v.x + v.y + v.z + v.w;
    float q = v.x * v.x + v.y * v.y + v.z * v.z + v.w * v.w;
    #pragma unroll
    for (int off = 32; off > 0; off >>= 1) {
        s += __shfl_xor(s, off, 64);
        q += __shfl_xor(q, off, 64);
    }
    float mean = s * (1.f / 256.f);
    float var  = q * (1.f / 256.f) - mean * mean;
    float rstd = rsqrtf(var + LN_EPS);
    float4 g = *(const float4*)(gamma + c4);
    float4 b = *(const float4*)(beta + c4);
    float4 o;
    o.x = (v.x - mean) * rstd * g.x + b.x;
    o.y = (v.y - mean) * rstd * g.y + b.y;
    o.z = (v.z - mean) * rstd * g.z + b.z;
    o.w = (v.w - mean) * rstd * g.w + b.w;
    *(float4*)(out + (size_t)node * OUT_DIM + c4) = o;
}

// ---------------- launch ----------------
extern "C" void kernel_launch(void* const* d_in, const int* in_sizes, int n_in,
                              void* d_out, int out_size, void* d_ws, size_t ws_size,
                              hipStream_t stream) {
    const float* x     = (const float*)d_in[0];
    const int*   src   = (const int*)d_in[1];
    const int*   dst   = (const int*)d_in[2];
    const float* Wself = (const float*)d_in[3];
    const float* rel   = (const float*)d_in[4];
    const float* gamma = (const float*)d_in[5];
    const float* beta  = (const float*)d_in[6];
    float* out = (float*)d_out;

    char* ws = (char*)d_ws;
    constexpr size_t BT_BYTES   = (size_t)N_COLS * IN_DIM * 2;
    constexpr size_t XB_BYTES   = (size_t)N_NODES * IN_DIM * 2;
    constexpr size_t H_BYTES    = (size_t)N_NODES * HC * 2;
    constexpr size_t OFFS_BYTES = 400128;
    constexpr size_t BKT_BYTES  = 4096;
    constexpr size_t EDGE_BYTES = (size_t)N_EDGES * 4;
    constexpr size_t NEED_A = BT_BYTES + XB_BYTES + H_BYTES + OFFS_BYTES + 3 * BKT_BYTES + EDGE_BYTES;

    const bool use_xb = (ws_size >= NEED_A);

    size_t off = 0;
    ushort_t* BT = (ushort_t*)(ws + off); off += BT_BYTES;
    ushort_t* xb = nullptr;
    if (use_xb) { xb = (ushort_t*)(ws + off); off += XB_BYTES; }
    ushort_t* H       = (ushort_t*)(ws + off); off += H_BYTES;
    uint2*    tmp     = (uint2*)H;
    int*      offs    = (int*)(ws + off); off += OFFS_BYTES;
    int*      bcount  = (int*)(ws + off); off += BKT_BYTES;
    int*      bbase   = (int*)(ws + off); off += BKT_BYTES;
    int*      bcursor = (int*)(ws + off); off += BKT_BYTES;
    uint_t*   edges   = (uint_t*)(ws + off);

    prep_w_kernel<<<(N_COLS * IN_DIM + 255) / 256, 256, 0, stream>>>(Wself, rel, BT);
    hipMemsetAsync(bcount, 0, NB * 4, stream);
    if (use_xb)
        conv_x_kernel<<<(N_NODES * IN_DIM / 8 + 255) / 256, 256, 0, stream>>>(x, xb);
    count_buckets<<<NWGE, 256, 0, stream>>>(dst, bcount);
    scan_buckets<<<1, 256, 0, stream>>>(bcount, bbase, bcursor);
    scatter_buckets<<<NWGE, 256, 0, stream>>>(src, dst, bcursor, tmp);
    build_csr<<<NB, 256, 0, stream>>>(tmp, bbase, offs, edges);

    dim3 ggrid(3, (N_NODES + BM - 1) / BM);
    for (int p = 0; p < N_PHASE - 1; ++p) {
        int c0 = p * CPH;
        if (use_xb)
            gemm_kernel<true><<<ggrid, 256, 0, stream>>>(xb, BT, H, N_NODES, c0);
        else
            gemm_kernel<false><<<ggrid, 256, 0, stream>>>(x, BT, H, N_NODES, c0);
        gather2_kernel<<<N_NODES / 8, 256, 0, stream>>>(H, offs, edges, out, c0);
    }
    if (use_xb)
        gemm_kernel<true><<<ggrid, 256, 0, stream>>>(xb, BT, H, N_NODES, 3 * CPH);
    else
        gemm_kernel<false><<<ggrid, 256, 0, stream>>>(x, BT, H, N_NODES, 3 * CPH);
    gather_ln_kernel<<<N_NODES / 4, 256, 0, stream>>>(H, offs, edges, out, gamma, beta);
}